// Round 13
// baseline (494.334 us; speedup 1.0000x reference)
//
#include <hip/hip_runtime.h>
#include <hip/hip_bf16.h>
#include <stdint.h>

// 2-layer GCN + global mean pool + MLP head. N=100000, E=1600000, G=512. fp32.
//
// Fully scalarized: the whole GNN reduces to 3 scalar segment-sums per node
// (deg; tf = sum xd[src]; (T,D,A) = sum (u,v,|u|)[src]) + a rank-3 epilogue:
//   h2[d,j] = relu(a*alpha_j + b*beta_j + c*gamma_j + b2_j), alpha/beta/gamma
//   fold W1/b1 through W2 (exact for any b1). Then mean-pool + MLP head.
//
// Round-13: XCD-private atomic accumulators replace the counting sort.
// Round-10 diagnosis refined: 150 MB HBM write for 4.8M shared-array atomics
// = dirty-line ping-pong between the 8 per-XCD L2s (2 atomics/line bounce).
// With 8 private copies (selected by s_getreg HW_REG_XCC_ID, measured working
// on gfx950 — learn_hip m09), every atomic line has ONE L2 owner: atomics
// retire in-L2, each copy (<=1.6 MB << 4 MiB L2) written back once. The
// hist/scanA/scanB/scatter pipeline and ebuf are deleted entirely.

static inline size_t align_up(size_t x, size_t a){ return (x + a - 1) & ~(a - 1); }

__device__ __forceinline__ int xcd_id(){
    unsigned v;
    asm volatile("s_getreg_b32 %0, hwreg(HW_REG_XCC_ID)" : "=s"(v));
    return (int)(v & 7u);
}

// --- edge pass 1: per-XCD degree histogram ---
__global__ void __launch_bounds__(256) k_deg8(const int* __restrict__ dst,
                                              int* __restrict__ deg8,
                                              int E, int npad){
    int* deg = deg8 + (size_t)xcd_id() * npad;
    int i0 = (blockIdx.x * 256 + threadIdx.x) * 4;
    if (i0 + 3 < E){
        int4 d = *(const int4*)(dst + i0);
        atomicAdd(&deg[d.x], 1);
        atomicAdd(&deg[d.y], 1);
        atomicAdd(&deg[d.z], 1);
        atomicAdd(&deg[d.w], 1);
    } else {
        for (int i = i0; i < E; ++i) atomicAdd(&deg[dst[i]], 1);
    }
}

// --- node pass 1: reduce deg copies -> dinv, xd = x*dinv ---
__global__ void __launch_bounds__(256) k_n1(
        const int* __restrict__ deg8, const float* __restrict__ x,
        float* __restrict__ dinv, float* __restrict__ xd, int N, int npad){
    int n = blockIdx.x * 256 + threadIdx.x;
    if (n >= N) return;
    int d = 0;
    #pragma unroll
    for (int c = 0; c < 8; ++c) d += deg8[(size_t)c * npad + n];
    float di = rsqrtf((float)d + 1.0f);
    dinv[n] = di;
    xd[n] = x[n] * di;
}

// --- edge pass 2: per-XCD tf[d] += xd[s] ---
__global__ void __launch_bounds__(256) k_tf8(
        const int* __restrict__ src, const int* __restrict__ dst,
        const float* __restrict__ xd, float* __restrict__ tf8,
        int E, int npad){
    float* tf = tf8 + (size_t)xcd_id() * npad;
    int i0 = (blockIdx.x * 256 + threadIdx.x) * 4;
    if (i0 + 3 < E){
        int4 s = *(const int4*)(src + i0);
        int4 d = *(const int4*)(dst + i0);
        float v0 = xd[s.x], v1 = xd[s.y], v2 = xd[s.z], v3 = xd[s.w];
        atomicAdd(&tf[d.x], v0);
        atomicAdd(&tf[d.y], v1);
        atomicAdd(&tf[d.z], v2);
        atomicAdd(&tf[d.w], v3);
    } else {
        for (int i = i0; i < E; ++i) atomicAdd(&tf[dst[i]], xd[src[i]]);
    }
}

// --- node pass 2: reduce tf copies -> uv = (dinv^2*(tf+xd), dinv) ---
__global__ void __launch_bounds__(256) k_n2(
        const float* __restrict__ tf8, const float* __restrict__ dinv,
        const float* __restrict__ xd, float2* __restrict__ uv, int N, int npad){
    int n = blockIdx.x * 256 + threadIdx.x;
    if (n >= N) return;
    float t = 0.f;
    #pragma unroll
    for (int c = 0; c < 8; ++c) t += tf8[(size_t)c * npad + n];
    float di = dinv[n];
    uv[n] = make_float2(di * di * (t + xd[n]), di);
}

// --- edge pass 3: per-XCD (T,D,A)[d] += (u_s, v_s, |u_s|) into float4 ---
__global__ void __launch_bounds__(256) k_tda8(
        const int* __restrict__ src, const int* __restrict__ dst,
        const float2* __restrict__ uv, float4* __restrict__ tda8,
        int E, int npad){
    float4* tda = tda8 + (size_t)xcd_id() * npad;
    int i0 = (blockIdx.x * 256 + threadIdx.x) * 4;
    if (i0 + 3 < E){
        int4 s = *(const int4*)(src + i0);
        int4 d = *(const int4*)(dst + i0);
        float2 u0 = uv[s.x], u1 = uv[s.y], u2 = uv[s.z], u3 = uv[s.w];
        float* p0 = (float*)&tda[d.x];
        float* p1 = (float*)&tda[d.y];
        float* p2 = (float*)&tda[d.z];
        float* p3 = (float*)&tda[d.w];
        atomicAdd(p0, u0.x); atomicAdd(p0 + 1, u0.y); atomicAdd(p0 + 2, fabsf(u0.x));
        atomicAdd(p1, u1.x); atomicAdd(p1 + 1, u1.y); atomicAdd(p1 + 2, fabsf(u1.x));
        atomicAdd(p2, u2.x); atomicAdd(p2 + 1, u2.y); atomicAdd(p2 + 2, fabsf(u2.x));
        atomicAdd(p3, u3.x); atomicAdd(p3 + 1, u3.y); atomicAdd(p3 + 2, fabsf(u3.x));
    } else {
        for (int i = i0; i < E; ++i){
            float2 u = uv[src[i]];
            float* p = (float*)&tda8[(size_t)xcd_id() * npad + dst[i]];
            atomicAdd(p, u.x); atomicAdd(p + 1, u.y); atomicAdd(p + 2, fabsf(u.x));
        }
    }
}

// --- node pass 3: reduce tda copies; abc = (dinv/2)*(T+u, D+v, A+|u|) ---
__global__ void __launch_bounds__(256) k_n3(
        const float4* __restrict__ tda8, const float2* __restrict__ uv,
        float4* __restrict__ abc, int N, int npad){
    int n = blockIdx.x * 256 + threadIdx.x;
    if (n >= N) return;
    float T = 0.f, D = 0.f, A = 0.f;
    #pragma unroll
    for (int c = 0; c < 8; ++c){
        float4 s = tda8[(size_t)c * npad + n];
        T += s.x; D += s.y; A += s.z;
    }
    float2 w = uv[n];
    float hv = 0.5f * w.y;
    abc[n] = make_float4(hv * (T + w.x), hv * (D + w.y),
                         hv * (A + fabsf(w.x)), 0.f);
}

// --- fused: abg fold + rank-3 relu -> mean pool -> MLP head. Block per graph. ---
#define NS 32
__global__ void __launch_bounds__(128) k_poolhead(
        const float4* __restrict__ abc, const int* __restrict__ batch,
        const float* __restrict__ W1, const float* __restrict__ b1,
        const float* __restrict__ W2, const float* __restrict__ b2,
        const float* __restrict__ Wl1, const float* __restrict__ bl1,
        const float* __restrict__ Wl2, const float* __restrict__ bl2,
        float* __restrict__ out, int N){
    __shared__ float4 st[NS];
    __shared__ float pooled[128];
    __shared__ float h3s[64];
    int g = blockIdx.x;
    int t = threadIdx.x;  // 128
    float al = 0.f, be = 0.f, ga = 0.f;
    #pragma unroll
    for (int c = 0; c < 64; ++c){
        float w2 = W2[c * 128 + t];
        al = fmaf(W1[c], w2, al);
        be = fmaf(b1[c], w2, be);
        ga = fmaf(fabsf(W1[c]), w2, ga);
    }
    float b2j = b2[t];
    int lo = 0, hi = N;
    while (lo < hi){ int m = (lo + hi) >> 1; if (batch[m] < g) lo = m + 1; else hi = m; }
    int lo2 = lo, hi2 = N;
    while (lo2 < hi2){ int m = (lo2 + hi2) >> 1; if (batch[m] < g + 1) lo2 = m + 1; else hi2 = m; }
    int cnt = lo2 - lo;
    float pool = 0.f;
    for (int base = lo; base < lo2; base += NS){
        int ns = min(NS, lo2 - base);
        if (t < 4 * ns) ((float*)st)[t] = ((const float*)(abc + base))[t];
        __syncthreads();
        for (int u = 0; u < ns; ++u){
            float4 s = st[u];
            float h = fmaf(s.x, al, fmaf(s.y, be, fmaf(s.z, ga, b2j)));
            pool += fmaxf(h, 0.f);
        }
        __syncthreads();
    }
    pooled[t] = pool / (float)(cnt > 0 ? cnt : 1);
    __syncthreads();
    if (t < 64){
        float a = bl1[t];
        #pragma unroll
        for (int k = 0; k < 128; ++k) a = fmaf(pooled[k], Wl1[k * 64 + t], a);
        h3s[t] = fmaxf(a, 0.f);
    }
    __syncthreads();
    if (t < 4){
        float o = bl2[t];
        #pragma unroll
        for (int j = 0; j < 64; ++j) o = fmaf(h3s[j], Wl2[j * 4 + t], o);
        out[g * 4 + t] = o;
    }
}

extern "C" void kernel_launch(void* const* d_in, const int* in_sizes, int n_in,
                              void* d_out, int out_size, void* d_ws, size_t ws_size,
                              hipStream_t stream) {
    const float* x    = (const float*)d_in[0];
    const int*   ei   = (const int*)d_in[1];
    const int*   batch= (const int*)d_in[2];
    const float* W1   = (const float*)d_in[3];
    const float* b1   = (const float*)d_in[4];
    const float* W2   = (const float*)d_in[5];
    const float* b2   = (const float*)d_in[6];
    const float* Wl1  = (const float*)d_in[7];
    const float* bl1  = (const float*)d_in[8];
    const float* Wl2  = (const float*)d_in[9];
    const float* bl2  = (const float*)d_in[10];

    const int N = in_sizes[0];
    const int E = in_sizes[1] / 2;
    const int G = out_size / 4;
    const int* srcp = ei;
    const int* dstp = ei + E;
    const int npad = (int)align_up((size_t)N, 1024);  // per-XCD copy stride

    // Workspace: 8 XCD-private accumulator copies first (one memset), then
    // node arrays (fully written before read).
    char* p = (char*)d_ws;
    size_t off = 0;
    int*    deg8 = (int*)(p + off);    off += align_up((size_t)npad * 8 * 4, 256);
    float*  tf8  = (float*)(p + off);  off += align_up((size_t)npad * 8 * 4, 256);
    float4* tda8 = (float4*)(p + off); off += align_up((size_t)npad * 8 * 16, 256);
    size_t zero_bytes = off;
    float*  dinv = (float*)(p + off);  off += align_up((size_t)N * 4, 16);
    float*  xd   = (float*)(p + off);  off += align_up((size_t)N * 4, 16);
    float2* uv   = (float2*)(p + off); off += align_up((size_t)N * 8, 16);
    float4* abc  = (float4*)(p + off); off += align_up((size_t)N * 16, 16);
    (void)ws_size; (void)n_in;

    hipMemsetAsync(d_ws, 0, zero_bytes, stream);

    const int EB = (E + 1023) / 1024;   // 4 edges/thread
    const int NB = (N + 255) / 256;

    k_deg8    <<<EB, 256, 0, stream>>>(dstp, deg8, E, npad);
    k_n1      <<<NB, 256, 0, stream>>>(deg8, x, dinv, xd, N, npad);
    k_tf8     <<<EB, 256, 0, stream>>>(srcp, dstp, xd, tf8, E, npad);
    k_n2      <<<NB, 256, 0, stream>>>(tf8, dinv, xd, uv, N, npad);
    k_tda8    <<<EB, 256, 0, stream>>>(srcp, dstp, uv, tda8, E, npad);
    k_n3      <<<NB, 256, 0, stream>>>(tda8, uv, abc, N, npad);
    k_poolhead<<<G, 128, 0, stream>>>(abc, batch, W1, b1, W2, b2,
                                      Wl1, bl1, Wl2, bl2, (float*)d_out, N);
}

// Round 14
// 165.738 us; speedup vs baseline: 2.9826x; 2.9826x over previous
//
#include <hip/hip_runtime.h>
#include <hip/hip_bf16.h>
#include <stdint.h>

// 2-layer GCN + global mean pool + MLP head. N=100000, E=1600000, G=512. fp32.
//
// Fully scalarized: the whole GNN reduces to 3 scalar segment-sums per node
// (deg; tf = sum xd[src]; (T,D,A) = sum (u,v,|u|)[src]) + a rank-3 epilogue:
//   h2[d,j] = relu(a*alpha_j + b*beta_j + c*gamma_j + b2_j), alpha/beta/gamma
//   fold W1/b1 through W2 (exact for any b1). Then mean-pool + MLP head.
//
// Round-13 lesson (measured): device-scope atomics execute past L2 at the
// memory-side coherence point (per-XCD L2s non-coherent) — XCD-private copies
// changed NOTHING (identical 150 MB WRITE). Scattered global atomics cost
// ~32 B fabric write each, capped ~670 GB/s. Never again at E-scale.
//
// Round-14: two-level counting sort down to NODE granularity. k_nsort
// (block per 256-node bucket) histograms its bucket -> per-node CSR offsets
// (degree falls out free: k_degxd absorbed) -> node-sorted ebuf2 (src only).
// k_t / k_tda become atomic-free, LDS-free thread-per-node register sums
// (kills the 8M LDS atomics the old bucket passes paid).

#define CHUNK   4096
#define MAXBUCK 400     // NBUCK = ceil(100000/256) = 391
#define BSH     8
#define BN      256

static inline size_t align_up(size_t x, size_t a){ return (x + a - 1) & ~(a - 1); }

// --- Pass A: per-chunk bucket histogram (LDS), 1024 thr = 1 int4/thread ---
__global__ void __launch_bounds__(1024) k_hist(const int* __restrict__ dst,
                                               int* __restrict__ hist, int E, int nbuck){
    __shared__ int h[MAXBUCK];
    int t = threadIdx.x;
    if (t < nbuck) h[t] = 0;
    __syncthreads();
    int base = blockIdx.x * CHUNK;
    int end = min(base + CHUNK, E);
    for (int i = base + t * 4; i + 3 < end; i += 4096){
        int4 d = *(const int4*)(dst + i);
        atomicAdd(&h[d.x >> BSH], 1);
        atomicAdd(&h[d.y >> BSH], 1);
        atomicAdd(&h[d.z >> BSH], 1);
        atomicAdd(&h[d.w >> BSH], 1);
    }
    int vend = base + ((end - base) & ~3);
    for (int i = vend + t; i < end; i += 1024) atomicAdd(&h[dst[i] >> BSH], 1);
    __syncthreads();
    if (t < nbuck) hist[(size_t)blockIdx.x * nbuck + t] = h[t];
}

// --- Pass B1: block-per-bucket parallel exclusive scan across chunks (nch<=512) ---
__global__ void __launch_bounds__(256) k_cscanA(int* __restrict__ hist,
                                                int* __restrict__ btot,
                                                int nch, int nbuck){
    __shared__ int sh[256];
    int b = blockIdx.x, t = threadIdx.x;
    int c0 = 2 * t, c1 = 2 * t + 1;
    int v0 = (c0 < nch) ? hist[(size_t)c0 * nbuck + b] : 0;
    int v1 = (c1 < nch) ? hist[(size_t)c1 * nbuck + b] : 0;
    sh[t] = v0 + v1; __syncthreads();
    for (int off = 1; off < 256; off <<= 1){
        int xv = (t >= off) ? sh[t - off] : 0;
        __syncthreads();
        if (t >= off) sh[t] += xv;
        __syncthreads();
    }
    int excl = (t == 0) ? 0 : sh[t - 1];
    if (c0 < nch) hist[(size_t)c0 * nbuck + b] = excl;
    if (c1 < nch) hist[(size_t)c1 * nbuck + b] = excl + v0;
    if (t == 255) btot[b] = sh[255];
}

// --- Pass B2: exclusive scan of bucket totals -> bucket base offsets ---
__global__ void k_cscanB(const int* __restrict__ btot, int* __restrict__ babs,
                         int nbuck, int E){
    __shared__ int sh[256];
    int t = threadIdx.x;
    int it = (nbuck + 255) / 256;  // 2
    int v[16];
    int sum = 0;
    int base = t * it;
    for (int u = 0; u < it; ++u){
        int idx = base + u;
        v[u] = (idx < nbuck) ? btot[idx] : 0;
        sum += v[u];
    }
    sh[t] = sum; __syncthreads();
    for (int off = 1; off < 256; off <<= 1){
        int xv = (t >= off) ? sh[t - off] : 0;
        __syncthreads();
        if (t >= off) sh[t] += xv;
        __syncthreads();
    }
    int run = (t == 0) ? 0 : sh[t - 1];
    for (int u = 0; u < it; ++u){
        int idx = base + u;
        if (idx < nbuck) babs[idx] = run;
        run += v[u];
    }
    if (t == 0) babs[nbuck] = E;
}

// --- Pass C: ordered scatter into bucket-grouped packed ebuf (LDS cursors) ---
__global__ void __launch_bounds__(1024) k_scatter(
        const int* __restrict__ src, const int* __restrict__ dst,
        const int* __restrict__ hist, const int* __restrict__ babs,
        int* __restrict__ ebuf, int E, int nbuck){
    __shared__ int lcur[MAXBUCK];
    int t = threadIdx.x;
    if (t < nbuck) lcur[t] = babs[t] + hist[(size_t)blockIdx.x * nbuck + t];
    __syncthreads();
    int base = blockIdx.x * CHUNK;
    int end = min(base + CHUNK, E);
    for (int i = base + t * 4; i + 3 < end; i += 4096){
        int4 s = *(const int4*)(src + i);
        int4 d = *(const int4*)(dst + i);
        int s0 = atomicAdd(&lcur[d.x >> BSH], 1);
        int s1 = atomicAdd(&lcur[d.y >> BSH], 1);
        int s2 = atomicAdd(&lcur[d.z >> BSH], 1);
        int s3 = atomicAdd(&lcur[d.w >> BSH], 1);
        ebuf[s0] = (s.x << BSH) | (d.x & (BN - 1));
        ebuf[s1] = (s.y << BSH) | (d.y & (BN - 1));
        ebuf[s2] = (s.z << BSH) | (d.z & (BN - 1));
        ebuf[s3] = (s.w << BSH) | (d.w & (BN - 1));
    }
    int vend = base + ((end - base) & ~3);
    for (int i = vend + t; i < end; i += 1024){
        int s = src[i], d = dst[i];
        int slot = atomicAdd(&lcur[d >> BSH], 1);
        ebuf[slot] = (s << BSH) | (d & (BN - 1));
    }
}

// --- Pass D: node-level sort within bucket; degree/dinv/xd fall out free ---
// block per bucket: LDS hist over 256 nodes -> local scan -> per-node CSR
// offsets noffs + node-sorted ebuf2 (src only). Scatter window = this
// bucket's 16 KB region, single-block-owned.
__global__ void __launch_bounds__(256) k_nsort(
        const int* __restrict__ ebuf, const int* __restrict__ babs,
        const float* __restrict__ x, float* __restrict__ dinv,
        float* __restrict__ xd, int* __restrict__ noffs,
        int* __restrict__ ebuf2, int N, int nbuck){
    __shared__ int cnt[BN], scn[BN], cur[BN];
    int b = blockIdx.x, node0 = b << BSH, t = threadIdx.x;
    int beg = babs[b], end = babs[b + 1];
    cnt[t] = 0;
    __syncthreads();
    for (int i = beg + t; i < end; i += 256)
        atomicAdd(&cnt[ebuf[i] & (BN - 1)], 1);
    __syncthreads();
    int myc = cnt[t];
    scn[t] = myc;
    __syncthreads();
    for (int off = 1; off < 256; off <<= 1){
        int xv = (t >= off) ? scn[t - off] : 0;
        __syncthreads();
        if (t >= off) scn[t] += xv;
        __syncthreads();
    }
    int excl = (t == 0) ? 0 : scn[t - 1];
    cur[t] = beg + excl;
    int n = node0 + t;
    if (n < N){
        noffs[n] = beg + excl;
        float di = rsqrtf((float)myc + 1.0f);
        dinv[n] = di;
        xd[n] = x[n] * di;
    }
    if (b == nbuck - 1 && t == 0) noffs[N] = end;
    __syncthreads();
    for (int i = beg + t; i < end; i += 256){
        int e = ebuf[i];
        int slot = atomicAdd(&cur[e & (BN - 1)], 1);
        ebuf2[slot] = e >> BSH;   // src index
    }
}

// --- pass E: tf[n] = sum xd[src] over CSR segment; uv = (dinv^2*(tf+xd), dinv) ---
// thread per node, register accumulation — no LDS, no atomics.
__global__ void __launch_bounds__(256) k_t(
        const int* __restrict__ ebuf2, const int* __restrict__ noffs,
        const float* __restrict__ xd, const float* __restrict__ dinv,
        float2* __restrict__ uv, int N){
    int n = blockIdx.x * 256 + threadIdx.x;
    if (n >= N) return;
    int beg = noffs[n], end = noffs[n + 1];
    float s = 0.f;
    for (int i = beg; i < end; ++i) s += xd[ebuf2[i]];
    float di = dinv[n];
    uv[n] = make_float2(di * di * (s + xd[n]), di);
}

// --- pass F: (T,D,A)[n] register sums; abc = (dinv/2)*(T+u, D+v, A+|u|) ---
__global__ void __launch_bounds__(256) k_tda(
        const int* __restrict__ ebuf2, const int* __restrict__ noffs,
        const float2* __restrict__ uv, float4* __restrict__ abc, int N){
    int n = blockIdx.x * 256 + threadIdx.x;
    if (n >= N) return;
    int beg = noffs[n], end = noffs[n + 1];
    float T = 0.f, D = 0.f, A = 0.f;
    for (int i = beg; i < end; ++i){
        float2 w = uv[ebuf2[i]];
        T += w.x; D += w.y; A += fabsf(w.x);
    }
    float2 w = uv[n];
    float hv = 0.5f * w.y;
    abc[n] = make_float4(hv * (T + w.x), hv * (D + w.y),
                         hv * (A + fabsf(w.x)), 0.f);
}

// --- fused: abg fold + rank-3 relu -> mean pool -> MLP head. Block per graph. ---
#define NS 32
__global__ void __launch_bounds__(128) k_poolhead(
        const float4* __restrict__ abc, const int* __restrict__ batch,
        const float* __restrict__ W1, const float* __restrict__ b1,
        const float* __restrict__ W2, const float* __restrict__ b2,
        const float* __restrict__ Wl1, const float* __restrict__ bl1,
        const float* __restrict__ Wl2, const float* __restrict__ bl2,
        float* __restrict__ out, int N){
    __shared__ float4 st[NS];
    __shared__ float pooled[128];
    __shared__ float h3s[64];
    int g = blockIdx.x;
    int t = threadIdx.x;  // 128
    float al = 0.f, be = 0.f, ga = 0.f;
    #pragma unroll
    for (int c = 0; c < 64; ++c){
        float w2 = W2[c * 128 + t];
        al = fmaf(W1[c], w2, al);
        be = fmaf(b1[c], w2, be);
        ga = fmaf(fabsf(W1[c]), w2, ga);
    }
    float b2j = b2[t];
    int lo = 0, hi = N;
    while (lo < hi){ int m = (lo + hi) >> 1; if (batch[m] < g) lo = m + 1; else hi = m; }
    int lo2 = lo, hi2 = N;
    while (lo2 < hi2){ int m = (lo2 + hi2) >> 1; if (batch[m] < g + 1) lo2 = m + 1; else hi2 = m; }
    int cnt = lo2 - lo;
    float pool = 0.f;
    for (int base = lo; base < lo2; base += NS){
        int ns = min(NS, lo2 - base);
        if (t < 4 * ns) ((float*)st)[t] = ((const float*)(abc + base))[t];
        __syncthreads();
        for (int u = 0; u < ns; ++u){
            float4 s = st[u];
            float h = fmaf(s.x, al, fmaf(s.y, be, fmaf(s.z, ga, b2j)));
            pool += fmaxf(h, 0.f);
        }
        __syncthreads();
    }
    pooled[t] = pool / (float)(cnt > 0 ? cnt : 1);
    __syncthreads();
    if (t < 64){
        float a = bl1[t];
        #pragma unroll
        for (int k = 0; k < 128; ++k) a = fmaf(pooled[k], Wl1[k * 64 + t], a);
        h3s[t] = fmaxf(a, 0.f);
    }
    __syncthreads();
    if (t < 4){
        float o = bl2[t];
        #pragma unroll
        for (int j = 0; j < 64; ++j) o = fmaf(h3s[j], Wl2[j * 4 + t], o);
        out[g * 4 + t] = o;
    }
}

extern "C" void kernel_launch(void* const* d_in, const int* in_sizes, int n_in,
                              void* d_out, int out_size, void* d_ws, size_t ws_size,
                              hipStream_t stream) {
    const float* x    = (const float*)d_in[0];
    const int*   ei   = (const int*)d_in[1];
    const int*   batch= (const int*)d_in[2];
    const float* W1   = (const float*)d_in[3];
    const float* b1   = (const float*)d_in[4];
    const float* W2   = (const float*)d_in[5];
    const float* b2   = (const float*)d_in[6];
    const float* Wl1  = (const float*)d_in[7];
    const float* bl1  = (const float*)d_in[8];
    const float* Wl2  = (const float*)d_in[9];
    const float* bl2  = (const float*)d_in[10];

    const int N = in_sizes[0];
    const int E = in_sizes[1] / 2;
    const int G = out_size / 4;
    const int* srcp = ei;
    const int* dstp = ei + E;
    const int NBUCK = (N + BN - 1) >> BSH;      // 391
    const int NCH   = (E + CHUNK - 1) / CHUNK;  // 391 (k_cscanA requires <=512)

    // Workspace (re-poisoned each call; every buffer fully written before read;
    // no memset needed, no global atomics anywhere).
    char* p = (char*)d_ws;
    size_t off = 0;
    int*    hist  = (int*)(p + off);    off += align_up((size_t)NCH * NBUCK * 4, 16);
    int*    btot  = (int*)(p + off);    off += align_up((size_t)NBUCK * 4, 16);
    int*    babs  = (int*)(p + off);    off += align_up((size_t)(NBUCK + 1) * 4, 16);
    int*    noffs = (int*)(p + off);    off += align_up((size_t)(N + 1) * 4, 16);
    float*  dinv  = (float*)(p + off);  off += align_up((size_t)N * 4, 16);
    float*  xd    = (float*)(p + off);  off += align_up((size_t)N * 4, 16);
    float2* uv    = (float2*)(p + off); off += align_up((size_t)N * 8, 16);
    float4* abc   = (float4*)(p + off); off += align_up((size_t)N * 16, 16);
    int*    ebuf  = (int*)(p + off);    off += align_up((size_t)E * 4, 16);
    int*    ebuf2 = (int*)(p + off);    off += align_up((size_t)E * 4, 16);
    (void)ws_size; (void)n_in;

    const int NB2 = (N + 255) / 256;

    k_hist    <<<NCH, 1024, 0, stream>>>(dstp, hist, E, NBUCK);
    k_cscanA  <<<NBUCK, 256, 0, stream>>>(hist, btot, NCH, NBUCK);
    k_cscanB  <<<1, 256, 0, stream>>>(btot, babs, NBUCK, E);
    k_scatter <<<NCH, 1024, 0, stream>>>(srcp, dstp, hist, babs, ebuf, E, NBUCK);
    k_nsort   <<<NBUCK, 256, 0, stream>>>(ebuf, babs, x, dinv, xd, noffs, ebuf2, N, NBUCK);
    k_t       <<<NB2, 256, 0, stream>>>(ebuf2, noffs, xd, dinv, uv, N);
    k_tda     <<<NB2, 256, 0, stream>>>(ebuf2, noffs, uv, abc, N);
    k_poolhead<<<G, 128, 0, stream>>>(abc, batch, W1, b1, W2, b2,
                                      Wl1, bl1, Wl2, bl2, (float*)d_out, N);
}